// Round 3
// baseline (637.337 us; speedup 1.0000x reference)
//
#include <hip/hip_runtime.h>

#define DIM 64
#define EPS 1e-12f
#define TMASK 0xFFFFF   // tail in low 20 bits, relation idx in high bits

__device__ __forceinline__ float wave_sum(float v) {
    #pragma unroll
    for (int off = 32; off; off >>= 1) v += __shfl_xor(v, off, 64);
    return v;
}
__device__ __forceinline__ float wave_max(float v) {
    #pragma unroll
    for (int off = 32; off; off >>= 1) v = fmaxf(v, __shfl_xor(v, off, 64));
    return v;
}

// out = ent, x0 = ent
__global__ void init_kernel(const float4* __restrict__ ent4,
                            float4* __restrict__ out4,
                            float4* __restrict__ x4, int n4) {
    int i = blockIdx.x * blockDim.x + threadIdx.x;
    if (i >= n4) return;
    float4 v = ent4[i];
    out4[i] = v;
    x4[i]   = v;
}

__global__ void hist_kernel(const int* __restrict__ head, int* __restrict__ counts, int E) {
    int e = blockIdx.x * blockDim.x + threadIdx.x;
    if (e < E) atomicAdd(&counts[head[e]], 1);
}

// single-block exclusive scan: counts[0..N) -> row_ptr[0..N], cursor copy
__global__ void scan_kernel(const int* __restrict__ counts,
                            int* __restrict__ row_ptr,
                            int* __restrict__ cursor, int N) {
    const int T = 1024;
    int tid = threadIdx.x;
    int chunk = (N + T - 1) / T;
    int beg = tid * chunk;
    int end = min(beg + chunk, N);
    int s = 0;
    for (int i = beg; i < end; ++i) s += counts[i];
    int lane = tid & 63, wid = tid >> 6;
    int v = s;
    #pragma unroll
    for (int off = 1; off < 64; off <<= 1) {
        int t = __shfl_up(v, off, 64);
        if (lane >= off) v += t;
    }
    __shared__ int wsum[16];
    __shared__ int wbase[16];
    if (lane == 63) wsum[wid] = v;
    __syncthreads();
    if (tid == 0) {
        int a = 0;
        for (int i = 0; i < 16; ++i) { wbase[i] = a; a += wsum[i]; }
    }
    __syncthreads();
    int run = wbase[wid] + v - s;   // exclusive prefix of this thread's chunk
    for (int i = beg; i < end; ++i) {
        row_ptr[i] = run;
        cursor[i]  = run;
        run += counts[i];
    }
    if (beg < N && end == N) row_ptr[N] = run;   // total
}

// CSR scatter; also records each edge's CSR slot (epos)
__global__ void scatter_kernel(const int* __restrict__ head,
                               const int* __restrict__ tail,
                               const int* __restrict__ etype,
                               int* __restrict__ cursor,
                               int* __restrict__ packed,
                               int* __restrict__ epos, int E) {
    int e = blockIdx.x * blockDim.x + threadIdx.x;
    if (e >= E) return;
    int h = head[e];
    int pos = atomicAdd(&cursor[h], 1);
    packed[pos] = (tail[e] & TMASK) | ((etype[e] - 1) << 20);
    epos[e] = pos;
}

// wave per edge: kg score, scattered into CSR slot
__global__ void edge_score_kernel(const float* __restrict__ ent,
                                  const float* __restrict__ relemb,
                                  const int* __restrict__ head,
                                  const int* __restrict__ tail,
                                  const int* __restrict__ etype,
                                  const int* __restrict__ epos,
                                  float* __restrict__ kg, int E, int R) {
    __shared__ float srel[2048];
    for (int i = threadIdx.x; i < R * DIM; i += blockDim.x) srel[i] = relemb[i];
    __syncthreads();
    int e    = (blockIdx.x * blockDim.x + threadIdx.x) >> 6;
    int lane = threadIdx.x & 63;
    if (e >= E) return;
    int h = head[e], t = tail[e], r = etype[e] - 1;
    float v = ent[h * DIM + lane] * srel[r * DIM + lane] * ent[t * DIM + lane];
    v = wave_sum(v);
    if (lane == 0) kg[epos[e]] = v;
}

// wave per node: stable softmax over contiguous CSR range (in-place on kg)
__global__ void node_softmax_kernel(const int* __restrict__ row_ptr,
                                    float* __restrict__ kg, int N) {
    int w    = (blockIdx.x * blockDim.x + threadIdx.x) >> 6;
    int lane = threadIdx.x & 63;
    if (w >= N) return;
    int beg = row_ptr[w], end = row_ptr[w + 1];
    if (beg == end) return;
    float m = -3.4e38f;
    for (int i = beg + lane; i < end; i += 64) m = fmaxf(m, kg[i]);
    m = wave_max(m);
    float s = 0.f;
    for (int i = beg + lane; i < end; i += 64) {
        float v = __expf(kg[i] - m);
        kg[i] = v;
        s += v;
    }
    s = wave_sum(s);
    float inv = 1.0f / s;
    for (int i = beg + lane; i < end; i += 64) kg[i] *= inv;
}

// wave per node: agg = sum(score * rel * x_old[tail]); normalize; out += ; x_new
// edges consumed in 64-wide chunks: coalesced load of packed/score, then
// shuffle-broadcast with 4-way unrolled independent gathers for MLP.
__global__ void hop_kernel(const float* __restrict__ relemb,
                           const int* __restrict__ row_ptr,
                           const int* __restrict__ packed,
                           const float* __restrict__ score,
                           const float* __restrict__ x_old,
                           float* __restrict__ x_new,
                           float* __restrict__ out, int N, int R) {
    __shared__ float srel[2048];
    for (int i = threadIdx.x; i < R * DIM; i += blockDim.x) srel[i] = relemb[i];
    __syncthreads();
    int w    = (blockIdx.x * blockDim.x + threadIdx.x) >> 6;
    int lane = threadIdx.x & 63;
    if (w >= N) return;
    int beg = row_ptr[w], end = row_ptr[w + 1];
    float acc = 0.f;
    for (int base = beg; base < end; base += 64) {
        int n = min(64, end - base);
        int   p  = 0;
        float sc = 0.f;
        if (lane < n) { p = packed[base + lane]; sc = score[base + lane]; }
        int j = 0;
        for (; j + 4 <= n; j += 4) {
            int   p0 = __shfl(p, j, 64),     p1 = __shfl(p, j + 1, 64);
            int   p2 = __shfl(p, j + 2, 64), p3 = __shfl(p, j + 3, 64);
            float s0 = __shfl(sc, j, 64),     s1 = __shfl(sc, j + 1, 64);
            float s2 = __shfl(sc, j + 2, 64), s3 = __shfl(sc, j + 3, 64);
            float a0 = x_old[(p0 & TMASK) * DIM + lane];
            float a1 = x_old[(p1 & TMASK) * DIM + lane];
            float a2 = x_old[(p2 & TMASK) * DIM + lane];
            float a3 = x_old[(p3 & TMASK) * DIM + lane];
            acc += s0 * srel[(p0 >> 20) * DIM + lane] * a0;
            acc += s1 * srel[(p1 >> 20) * DIM + lane] * a1;
            acc += s2 * srel[(p2 >> 20) * DIM + lane] * a2;
            acc += s3 * srel[(p3 >> 20) * DIM + lane] * a3;
        }
        for (; j < n; ++j) {
            int   pj = __shfl(p, j, 64);
            float sj = __shfl(sc, j, 64);
            acc += sj * srel[(pj >> 20) * DIM + lane] * x_old[(pj & TMASK) * DIM + lane];
        }
    }
    float s = wave_sum(acc * acc);
    float xn = acc / fmaxf(sqrtf(s), EPS);
    x_new[w * DIM + lane] = xn;
    out[w * DIM + lane]  += xn;
}

extern "C" void kernel_launch(void* const* d_in, const int* in_sizes, int n_in,
                              void* d_out, int out_size, void* d_ws, size_t ws_size,
                              hipStream_t stream) {
    const float* ent    = (const float*)d_in[0];
    const float* relemb = (const float*)d_in[1];
    const int*   eidx   = (const int*)d_in[2];
    const int*   etype  = (const int*)d_in[3];
    float* out = (float*)d_out;

    const int N = in_sizes[0] / DIM;   // 50000
    const int R = in_sizes[1] / DIM;   // 20
    const int E = in_sizes[3];         // 800000
    const int* head = eidx;
    const int* tail = eidx + E;

    char* ws = (char*)d_ws;
    size_t off = 0;
    auto alloc = [&](size_t bytes) {
        char* p = ws + off;
        off += (bytes + 255) & ~size_t(255);
        return p;
    };
    int*   counts  = (int*)alloc((size_t)N * 4);
    int*   row_ptr = (int*)alloc((size_t)(N + 1) * 4);
    int*   cursor  = (int*)alloc((size_t)N * 4);
    int*   packed  = (int*)alloc((size_t)E * 4);
    int*   epos    = (int*)alloc((size_t)E * 4);
    float* score   = (float*)alloc((size_t)E * 4);   // kg, then softmax in-place
    float* x0      = (float*)alloc((size_t)N * DIM * 4);
    float* x1      = (float*)alloc((size_t)N * DIM * 4);
    (void)ws_size;

    hipMemsetAsync(counts, 0, (size_t)N * 4, stream);

    // init out = x0 = ent
    {
        int n4 = N * DIM / 4;
        init_kernel<<<(n4 + 255) / 256, 256, 0, stream>>>(
            (const float4*)ent, (float4*)out, (float4*)x0, n4);
    }

    // CSR by head
    hist_kernel<<<(E + 255) / 256, 256, 0, stream>>>(head, counts, E);
    scan_kernel<<<1, 1024, 0, stream>>>(counts, row_ptr, cursor, N);
    scatter_kernel<<<(E + 255) / 256, 256, 0, stream>>>(head, tail, etype, cursor,
                                                        packed, epos, E);

    // per-edge scores scattered into CSR order, then per-node softmax
    int edgeBlocks = (E + 3) / 4;   // wave per edge, 4 waves/block
    edge_score_kernel<<<edgeBlocks, 256, 0, stream>>>(ent, relemb, head, tail, etype,
                                                      epos, score, E, R);
    int nodeBlocks = (N + 3) / 4;
    node_softmax_kernel<<<nodeBlocks, 256, 0, stream>>>(row_ptr, score, N);

    // 3 hops, ping-pong x
    hop_kernel<<<nodeBlocks, 256, 0, stream>>>(relemb, row_ptr, packed, score, x0, x1, out, N, R);
    hop_kernel<<<nodeBlocks, 256, 0, stream>>>(relemb, row_ptr, packed, score, x1, x0, out, N, R);
    hop_kernel<<<nodeBlocks, 256, 0, stream>>>(relemb, row_ptr, packed, score, x0, x1, out, N, R);
}

// Round 4
// 396.680 us; speedup vs baseline: 1.6067x; 1.6067x over previous
//
#include <hip/hip_runtime.h>

#define DIM 64
#define EPS 1e-12f
#define TMASK 0xFFFFF   // tail in low 20 bits, relation idx in high bits

__device__ __forceinline__ float wave_sum(float v) {
    #pragma unroll
    for (int off = 32; off; off >>= 1) v += __shfl_xor(v, off, 64);
    return v;
}

__device__ __forceinline__ float bf2f(unsigned short u) {
    return __uint_as_float(((unsigned)u) << 16);
}
__device__ __forceinline__ unsigned short f2bf(float f) {
    unsigned u = __float_as_uint(f);
    u += 0x7FFFu + ((u >> 16) & 1u);   // round-to-nearest-even
    return (unsigned short)(u >> 16);
}

// out = ent (f32), xb0 = bf16(ent)
__global__ void init_kernel(const float4* __restrict__ ent4,
                            float4* __restrict__ out4,
                            ushort4* __restrict__ xb4, int n4) {
    int i = blockIdx.x * blockDim.x + threadIdx.x;
    if (i >= n4) return;
    float4 v = ent4[i];
    out4[i] = v;
    ushort4 b;
    b.x = f2bf(v.x); b.y = f2bf(v.y); b.z = f2bf(v.z); b.w = f2bf(v.w);
    xb4[i] = b;
}

__global__ void hist_kernel(const int* __restrict__ head, int* __restrict__ counts, int E) {
    int e = blockIdx.x * blockDim.x + threadIdx.x;
    if (e < E) atomicAdd(&counts[head[e]], 1);
}

// single-block exclusive scan: counts[0..N) -> row_ptr[0..N], cursor copy
__global__ void scan_kernel(const int* __restrict__ counts,
                            int* __restrict__ row_ptr,
                            int* __restrict__ cursor, int N) {
    const int T = 1024;
    int tid = threadIdx.x;
    int chunk = (N + T - 1) / T;
    int beg = tid * chunk;
    int end = min(beg + chunk, N);
    int s = 0;
    for (int i = beg; i < end; ++i) s += counts[i];
    int lane = tid & 63, wid = tid >> 6;
    int v = s;
    #pragma unroll
    for (int off = 1; off < 64; off <<= 1) {
        int t = __shfl_up(v, off, 64);
        if (lane >= off) v += t;
    }
    __shared__ int wsum[16];
    __shared__ int wbase[16];
    if (lane == 63) wsum[wid] = v;
    __syncthreads();
    if (tid == 0) {
        int a = 0;
        for (int i = 0; i < 16; ++i) { wbase[i] = a; a += wsum[i]; }
    }
    __syncthreads();
    int run = wbase[wid] + v - s;   // exclusive prefix of this thread's chunk
    for (int i = beg; i < end; ++i) {
        row_ptr[i] = run;
        cursor[i]  = run;
        run += counts[i];
    }
    if (beg < N && end == N) row_ptr[N] = run;   // total
}

__global__ void scatter_kernel(const int* __restrict__ head,
                               const int* __restrict__ tail,
                               const int* __restrict__ etype,
                               int* __restrict__ cursor,
                               int* __restrict__ packed, int E) {
    int e = blockIdx.x * blockDim.x + threadIdx.x;
    if (e >= E) return;
    int h = head[e];
    int pos = atomicAdd(&cursor[h], 1);
    packed[pos] = (tail[e] & TMASK) | ((etype[e] - 1) << 20);
}

// wave per node: kg scores (chunked broadcast, unrolled bf16 gathers) + stable softmax
__global__ void score_softmax_kernel(const float* __restrict__ ent,
                                     const unsigned short* __restrict__ entb,
                                     const float* __restrict__ relemb,
                                     const int* __restrict__ row_ptr,
                                     const int* __restrict__ packed,
                                     float* __restrict__ score, int N, int R) {
    __shared__ float srel[2048];
    for (int i = threadIdx.x; i < R * DIM; i += blockDim.x) srel[i] = relemb[i];
    __syncthreads();
    int w    = (blockIdx.x * blockDim.x + threadIdx.x) >> 6;
    int lane = threadIdx.x & 63;
    if (w >= N) return;
    int beg = row_ptr[w], end = row_ptr[w + 1];
    if (beg == end) return;
    float eh = ent[w * DIM + lane];
    float m = -3.4e38f;
    for (int base = beg; base < end; base += 64) {
        int n = min(64, end - base);
        int p = 0;
        if (lane < n) p = packed[base + lane];
        float myv = 0.f;
        int j = 0;
        for (; j + 4 <= n; j += 4) {
            int p0 = __shfl(p, j, 64),     p1 = __shfl(p, j + 1, 64);
            int p2 = __shfl(p, j + 2, 64), p3 = __shfl(p, j + 3, 64);
            float g0 = bf2f(entb[(p0 & TMASK) * DIM + lane]);
            float g1 = bf2f(entb[(p1 & TMASK) * DIM + lane]);
            float g2 = bf2f(entb[(p2 & TMASK) * DIM + lane]);
            float g3 = bf2f(entb[(p3 & TMASK) * DIM + lane]);
            float v0 = wave_sum(eh * srel[(p0 >> 20) * DIM + lane] * g0);
            float v1 = wave_sum(eh * srel[(p1 >> 20) * DIM + lane] * g1);
            float v2 = wave_sum(eh * srel[(p2 >> 20) * DIM + lane] * g2);
            float v3 = wave_sum(eh * srel[(p3 >> 20) * DIM + lane] * g3);
            if (lane == j)     myv = v0;
            if (lane == j + 1) myv = v1;
            if (lane == j + 2) myv = v2;
            if (lane == j + 3) myv = v3;
            m = fmaxf(m, fmaxf(fmaxf(v0, v1), fmaxf(v2, v3)));
        }
        for (; j < n; ++j) {
            int pj = __shfl(p, j, 64);
            float v = wave_sum(eh * srel[(pj >> 20) * DIM + lane] *
                               bf2f(entb[(pj & TMASK) * DIM + lane]));
            if (lane == j) myv = v;
            m = fmaxf(m, v);
        }
        if (lane < n) score[base + lane] = myv;  // owner lane == (i-beg)&63
    }
    // m is wave-uniform (wave_sum is an all-reduce)
    float s = 0.f;
    for (int i = beg + lane; i < end; i += 64) {
        float v = __expf(score[i] - m);   // re-reads own store
        score[i] = v;
        s += v;
    }
    s = wave_sum(s);
    float inv = 1.0f / s;
    for (int i = beg + lane; i < end; i += 64) score[i] *= inv;
}

// wave per node: agg = sum(score * rel * x_old[tail]); normalize; out +=; x_new (bf16)
__global__ void hop_kernel(const float* __restrict__ relemb,
                           const int* __restrict__ row_ptr,
                           const int* __restrict__ packed,
                           const float* __restrict__ score,
                           const unsigned short* __restrict__ xb_old,
                           unsigned short* __restrict__ xb_new,
                           float* __restrict__ out, int N, int R) {
    __shared__ float srel[2048];
    for (int i = threadIdx.x; i < R * DIM; i += blockDim.x) srel[i] = relemb[i];
    __syncthreads();
    int w    = (blockIdx.x * blockDim.x + threadIdx.x) >> 6;
    int lane = threadIdx.x & 63;
    if (w >= N) return;
    int beg = row_ptr[w], end = row_ptr[w + 1];
    float acc = 0.f;
    for (int base = beg; base < end; base += 64) {
        int n = min(64, end - base);
        int   p  = 0;
        float sc = 0.f;
        if (lane < n) { p = packed[base + lane]; sc = score[base + lane]; }
        int j = 0;
        for (; j + 4 <= n; j += 4) {
            int   p0 = __shfl(p, j, 64),     p1 = __shfl(p, j + 1, 64);
            int   p2 = __shfl(p, j + 2, 64), p3 = __shfl(p, j + 3, 64);
            float s0 = __shfl(sc, j, 64),     s1 = __shfl(sc, j + 1, 64);
            float s2 = __shfl(sc, j + 2, 64), s3 = __shfl(sc, j + 3, 64);
            float a0 = bf2f(xb_old[(p0 & TMASK) * DIM + lane]);
            float a1 = bf2f(xb_old[(p1 & TMASK) * DIM + lane]);
            float a2 = bf2f(xb_old[(p2 & TMASK) * DIM + lane]);
            float a3 = bf2f(xb_old[(p3 & TMASK) * DIM + lane]);
            acc += s0 * srel[(p0 >> 20) * DIM + lane] * a0;
            acc += s1 * srel[(p1 >> 20) * DIM + lane] * a1;
            acc += s2 * srel[(p2 >> 20) * DIM + lane] * a2;
            acc += s3 * srel[(p3 >> 20) * DIM + lane] * a3;
        }
        for (; j < n; ++j) {
            int   pj = __shfl(p, j, 64);
            float sj = __shfl(sc, j, 64);
            acc += sj * srel[(pj >> 20) * DIM + lane] *
                   bf2f(xb_old[(pj & TMASK) * DIM + lane]);
        }
    }
    float s = wave_sum(acc * acc);
    float xn = acc / fmaxf(sqrtf(s), EPS);
    xb_new[w * DIM + lane] = f2bf(xn);
    out[w * DIM + lane]  += xn;
}

extern "C" void kernel_launch(void* const* d_in, const int* in_sizes, int n_in,
                              void* d_out, int out_size, void* d_ws, size_t ws_size,
                              hipStream_t stream) {
    const float* ent    = (const float*)d_in[0];
    const float* relemb = (const float*)d_in[1];
    const int*   eidx   = (const int*)d_in[2];
    const int*   etype  = (const int*)d_in[3];
    float* out = (float*)d_out;

    const int N = in_sizes[0] / DIM;   // 50000
    const int R = in_sizes[1] / DIM;   // 20
    const int E = in_sizes[3];         // 800000
    const int* head = eidx;
    const int* tail = eidx + E;

    char* ws = (char*)d_ws;
    size_t off = 0;
    auto alloc = [&](size_t bytes) {
        char* p = ws + off;
        off += (bytes + 255) & ~size_t(255);
        return p;
    };
    int*   counts  = (int*)alloc((size_t)N * 4);
    int*   row_ptr = (int*)alloc((size_t)(N + 1) * 4);
    int*   cursor  = (int*)alloc((size_t)N * 4);
    int*   packed  = (int*)alloc((size_t)E * 4);
    float* score   = (float*)alloc((size_t)E * 4);
    unsigned short* xb0 = (unsigned short*)alloc((size_t)N * DIM * 2);
    unsigned short* xb1 = (unsigned short*)alloc((size_t)N * DIM * 2);
    (void)ws_size;

    hipMemsetAsync(counts, 0, (size_t)N * 4, stream);

    // init out = ent, xb0 = bf16(ent)  (xb0 doubles as the score-phase gather copy)
    {
        int n4 = N * DIM / 4;
        init_kernel<<<(n4 + 255) / 256, 256, 0, stream>>>(
            (const float4*)ent, (float4*)out, (ushort4*)xb0, n4);
    }

    // CSR by head
    hist_kernel<<<(E + 255) / 256, 256, 0, stream>>>(head, counts, E);
    scan_kernel<<<1, 1024, 0, stream>>>(counts, row_ptr, cursor, N);
    scatter_kernel<<<(E + 255) / 256, 256, 0, stream>>>(head, tail, etype, cursor,
                                                        packed, E);

    int nodeBlocks = (N + 3) / 4;   // 4 waves / block
    score_softmax_kernel<<<nodeBlocks, 256, 0, stream>>>(ent, xb0, relemb, row_ptr,
                                                         packed, score, N, R);

    // 3 hops, ping-pong bf16 x
    hop_kernel<<<nodeBlocks, 256, 0, stream>>>(relemb, row_ptr, packed, score, xb0, xb1, out, N, R);
    hop_kernel<<<nodeBlocks, 256, 0, stream>>>(relemb, row_ptr, packed, score, xb1, xb0, out, N, R);
    hop_kernel<<<nodeBlocks, 256, 0, stream>>>(relemb, row_ptr, packed, score, xb0, xb1, out, N, R);
}

// Round 5
// 303.047 us; speedup vs baseline: 2.1031x; 1.3090x over previous
//
#include <hip/hip_runtime.h>
#include <hip/hip_fp16.h>

#define DIM 64
#define EPS 1e-12f
#define TMASK 0xFFFFF   // tail in low 20 bits, relation idx in high bits

__device__ __forceinline__ float wave_sum(float v) {
    #pragma unroll
    for (int off = 32; off; off >>= 1) v += __shfl_xor(v, off, 64);
    return v;
}

// out = ent (f32), xh0 = fp16(ent)
__global__ void init_kernel(const float4* __restrict__ ent4,
                            float4* __restrict__ out4,
                            ushort4* __restrict__ xh4, int n4) {
    int i = blockIdx.x * blockDim.x + threadIdx.x;
    if (i >= n4) return;
    float4 v = ent4[i];
    out4[i] = v;
    ushort4 b;
    b.x = __half_as_ushort(__float2half(v.x));
    b.y = __half_as_ushort(__float2half(v.y));
    b.z = __half_as_ushort(__float2half(v.z));
    b.w = __half_as_ushort(__float2half(v.w));
    xh4[i] = b;
}

__global__ void hist_kernel(const int* __restrict__ head, int* __restrict__ counts, int E) {
    int e = blockIdx.x * blockDim.x + threadIdx.x;
    if (e < E) atomicAdd(&counts[head[e]], 1);
}

// ---- parallel scan: A) per-block sums, B) scan block sums, C) per-block scan ----
__global__ void bsum_kernel(const int* __restrict__ counts, int* __restrict__ bsum, int N) {
    int tid = threadIdx.x;
    int i = blockIdx.x * 1024 + tid;
    int v = (i < N) ? counts[i] : 0;
    int lane = tid & 63, wid = tid >> 6;
    #pragma unroll
    for (int off = 32; off; off >>= 1) v += __shfl_xor(v, off, 64);
    __shared__ int ws[16];
    if (lane == 0) ws[wid] = v;
    __syncthreads();
    if (tid == 0) {
        int a = 0;
        #pragma unroll
        for (int k = 0; k < 16; ++k) a += ws[k];
        bsum[blockIdx.x] = a;
    }
}

__global__ void bscan_kernel(const int* __restrict__ bsum, int* __restrict__ boff, int nb) {
    if (nb > 64) {                      // safety fallback (not hit at N=50000)
        if (threadIdx.x == 0) {
            int a = 0;
            for (int i = 0; i < nb; ++i) { boff[i] = a; a += bsum[i]; }
        }
        return;
    }
    int lane = threadIdx.x;
    int v = (lane < nb) ? bsum[lane] : 0;
    int inc = v;
    #pragma unroll
    for (int off = 1; off < 64; off <<= 1) {
        int t = __shfl_up(inc, off, 64);
        if (lane >= off) inc += t;
    }
    if (lane < nb) boff[lane] = inc - v;   // exclusive
}

__global__ void scan2_kernel(const int* __restrict__ counts,
                             const int* __restrict__ boff,
                             int* __restrict__ row_ptr,
                             int* __restrict__ cursor, int N, int E) {
    int tid = threadIdx.x;
    int i = blockIdx.x * 1024 + tid;
    int v = (i < N) ? counts[i] : 0;
    int lane = tid & 63, wid = tid >> 6;
    int inc = v;
    #pragma unroll
    for (int off = 1; off < 64; off <<= 1) {
        int t = __shfl_up(inc, off, 64);
        if (lane >= off) inc += t;
    }
    __shared__ int wsum[16], wpre[16];
    if (lane == 63) wsum[wid] = inc;
    __syncthreads();
    if (tid == 0) {
        int a = 0;
        #pragma unroll
        for (int k = 0; k < 16; ++k) { wpre[k] = a; a += wsum[k]; }
    }
    __syncthreads();
    int excl = boff[blockIdx.x] + wpre[wid] + inc - v;
    if (i < N) { row_ptr[i] = excl; cursor[i] = excl; }
    if (i == 0) row_ptr[N] = E;
}

__global__ void scatter_kernel(const int* __restrict__ head,
                               const int* __restrict__ tail,
                               const int* __restrict__ etype,
                               int* __restrict__ cursor,
                               int* __restrict__ packed, int E) {
    int e = blockIdx.x * blockDim.x + threadIdx.x;
    if (e >= E) return;
    int h = head[e];
    int pos = atomicAdd(&cursor[h], 1);
    packed[pos] = (tail[e] & TMASK) | ((etype[e] - 1) << 20);
}

// wave per node: kg scores (chunked broadcast, unrolled fp16 gathers) + stable softmax
__global__ void score_softmax_kernel(const float* __restrict__ ent,
                                     const __half* __restrict__ enth,
                                     const float* __restrict__ relemb,
                                     const int* __restrict__ row_ptr,
                                     const int* __restrict__ packed,
                                     float* __restrict__ score, int N, int R) {
    __shared__ float srel[2048];
    for (int i = threadIdx.x; i < R * DIM; i += blockDim.x) srel[i] = relemb[i];
    __syncthreads();
    int w    = (blockIdx.x * blockDim.x + threadIdx.x) >> 6;
    int lane = threadIdx.x & 63;
    if (w >= N) return;
    int beg = row_ptr[w], end = row_ptr[w + 1];
    if (beg == end) return;
    float eh = ent[w * DIM + lane];
    float m = -3.4e38f;
    for (int base = beg; base < end; base += 64) {
        int n = min(64, end - base);
        int p = 0;
        if (lane < n) p = packed[base + lane];
        float myv = 0.f;
        int j = 0;
        for (; j + 4 <= n; j += 4) {
            int p0 = __shfl(p, j, 64),     p1 = __shfl(p, j + 1, 64);
            int p2 = __shfl(p, j + 2, 64), p3 = __shfl(p, j + 3, 64);
            float g0 = __half2float(enth[(p0 & TMASK) * DIM + lane]);
            float g1 = __half2float(enth[(p1 & TMASK) * DIM + lane]);
            float g2 = __half2float(enth[(p2 & TMASK) * DIM + lane]);
            float g3 = __half2float(enth[(p3 & TMASK) * DIM + lane]);
            float v0 = wave_sum(eh * srel[(p0 >> 20) * DIM + lane] * g0);
            float v1 = wave_sum(eh * srel[(p1 >> 20) * DIM + lane] * g1);
            float v2 = wave_sum(eh * srel[(p2 >> 20) * DIM + lane] * g2);
            float v3 = wave_sum(eh * srel[(p3 >> 20) * DIM + lane] * g3);
            if (lane == j)     myv = v0;
            if (lane == j + 1) myv = v1;
            if (lane == j + 2) myv = v2;
            if (lane == j + 3) myv = v3;
            m = fmaxf(m, fmaxf(fmaxf(v0, v1), fmaxf(v2, v3)));
        }
        for (; j < n; ++j) {
            int pj = __shfl(p, j, 64);
            float v = wave_sum(eh * srel[(pj >> 20) * DIM + lane] *
                               __half2float(enth[(pj & TMASK) * DIM + lane]));
            if (lane == j) myv = v;
            m = fmaxf(m, v);
        }
        if (lane < n) score[base + lane] = myv;  // owner lane == (i-beg)&63
    }
    // m is wave-uniform (wave_sum is an all-reduce)
    float s = 0.f;
    for (int i = beg + lane; i < end; i += 64) {
        float v = __expf(score[i] - m);
        score[i] = v;
        s += v;
    }
    s = wave_sum(s);
    float inv = 1.0f / s;
    for (int i = beg + lane; i < end; i += 64) score[i] *= inv;
}

// wave per node: agg = sum(score * rel * x_old[tail]); normalize; out +=; x_new (fp16)
__global__ void hop_kernel(const float* __restrict__ relemb,
                           const int* __restrict__ row_ptr,
                           const int* __restrict__ packed,
                           const float* __restrict__ score,
                           const __half* __restrict__ xh_old,
                           __half* __restrict__ xh_new,
                           float* __restrict__ out, int N, int R) {
    __shared__ float srel[2048];
    for (int i = threadIdx.x; i < R * DIM; i += blockDim.x) srel[i] = relemb[i];
    __syncthreads();
    int w    = (blockIdx.x * blockDim.x + threadIdx.x) >> 6;
    int lane = threadIdx.x & 63;
    if (w >= N) return;
    int beg = row_ptr[w], end = row_ptr[w + 1];
    float acc = 0.f;
    for (int base = beg; base < end; base += 64) {
        int n = min(64, end - base);
        int   p  = 0;
        float sc = 0.f;
        if (lane < n) { p = packed[base + lane]; sc = score[base + lane]; }
        int j = 0;
        for (; j + 4 <= n; j += 4) {
            int   p0 = __shfl(p, j, 64),     p1 = __shfl(p, j + 1, 64);
            int   p2 = __shfl(p, j + 2, 64), p3 = __shfl(p, j + 3, 64);
            float s0 = __shfl(sc, j, 64),     s1 = __shfl(sc, j + 1, 64);
            float s2 = __shfl(sc, j + 2, 64), s3 = __shfl(sc, j + 3, 64);
            float a0 = __half2float(xh_old[(p0 & TMASK) * DIM + lane]);
            float a1 = __half2float(xh_old[(p1 & TMASK) * DIM + lane]);
            float a2 = __half2float(xh_old[(p2 & TMASK) * DIM + lane]);
            float a3 = __half2float(xh_old[(p3 & TMASK) * DIM + lane]);
            acc += s0 * srel[(p0 >> 20) * DIM + lane] * a0;
            acc += s1 * srel[(p1 >> 20) * DIM + lane] * a1;
            acc += s2 * srel[(p2 >> 20) * DIM + lane] * a2;
            acc += s3 * srel[(p3 >> 20) * DIM + lane] * a3;
        }
        for (; j < n; ++j) {
            int   pj = __shfl(p, j, 64);
            float sj = __shfl(sc, j, 64);
            acc += sj * srel[(pj >> 20) * DIM + lane] *
                   __half2float(xh_old[(pj & TMASK) * DIM + lane]);
        }
    }
    float s = wave_sum(acc * acc);
    float xn = acc / fmaxf(sqrtf(s), EPS);
    xh_new[w * DIM + lane] = __float2half(xn);
    out[w * DIM + lane]  += xn;
}

extern "C" void kernel_launch(void* const* d_in, const int* in_sizes, int n_in,
                              void* d_out, int out_size, void* d_ws, size_t ws_size,
                              hipStream_t stream) {
    const float* ent    = (const float*)d_in[0];
    const float* relemb = (const float*)d_in[1];
    const int*   eidx   = (const int*)d_in[2];
    const int*   etype  = (const int*)d_in[3];
    float* out = (float*)d_out;

    const int N = in_sizes[0] / DIM;   // 50000
    const int R = in_sizes[1] / DIM;   // 20
    const int E = in_sizes[3];         // 800000
    const int* head = eidx;
    const int* tail = eidx + E;

    char* ws = (char*)d_ws;
    size_t off = 0;
    auto alloc = [&](size_t bytes) {
        char* p = ws + off;
        off += (bytes + 255) & ~size_t(255);
        return p;
    };
    int*   counts  = (int*)alloc((size_t)N * 4);
    int*   row_ptr = (int*)alloc((size_t)(N + 1) * 4);
    int*   cursor  = (int*)alloc((size_t)N * 4);
    int*   bsum    = (int*)alloc(64 * 4);
    int*   boff    = (int*)alloc(64 * 4);
    int*   packed  = (int*)alloc((size_t)E * 4);
    float* score   = (float*)alloc((size_t)E * 4);
    __half* xh0    = (__half*)alloc((size_t)N * DIM * 2);
    __half* xh1    = (__half*)alloc((size_t)N * DIM * 2);
    (void)ws_size;

    hipMemsetAsync(counts, 0, (size_t)N * 4, stream);

    // init out = ent, xh0 = fp16(ent)  (xh0 doubles as the score-phase gather copy)
    {
        int n4 = N * DIM / 4;
        init_kernel<<<(n4 + 255) / 256, 256, 0, stream>>>(
            (const float4*)ent, (float4*)out, (ushort4*)xh0, n4);
    }

    // CSR by head (parallel scan)
    int nb = (N + 1023) / 1024;
    hist_kernel<<<(E + 255) / 256, 256, 0, stream>>>(head, counts, E);
    bsum_kernel<<<nb, 1024, 0, stream>>>(counts, bsum, N);
    bscan_kernel<<<1, 64, 0, stream>>>(bsum, boff, nb);
    scan2_kernel<<<nb, 1024, 0, stream>>>(counts, boff, row_ptr, cursor, N, E);
    scatter_kernel<<<(E + 255) / 256, 256, 0, stream>>>(head, tail, etype, cursor,
                                                        packed, E);

    int nodeBlocks = (N + 3) / 4;   // 4 waves / block
    score_softmax_kernel<<<nodeBlocks, 256, 0, stream>>>(ent, xh0, relemb, row_ptr,
                                                         packed, score, N, R);

    // 3 hops, ping-pong fp16 x
    hop_kernel<<<nodeBlocks, 256, 0, stream>>>(relemb, row_ptr, packed, score, xh0, xh1, out, N, R);
    hop_kernel<<<nodeBlocks, 256, 0, stream>>>(relemb, row_ptr, packed, score, xh1, xh0, out, N, R);
    hop_kernel<<<nodeBlocks, 256, 0, stream>>>(relemb, row_ptr, packed, score, xh0, xh1, out, N, R);
}

// Round 6
// 285.181 us; speedup vs baseline: 2.2349x; 1.0626x over previous
//
#include <hip/hip_runtime.h>
#include <hip/hip_fp16.h>

#define DIM 64
#define EPS 1e-12f
#define TMASK 0xFFFFF   // tail in low 20 bits, relation idx in high bits

__device__ __forceinline__ float wave_sum(float v) {
    #pragma unroll
    for (int off = 32; off; off >>= 1) v += __shfl_xor(v, off, 64);
    return v;
}
__device__ __forceinline__ float wave_max(float v) {
    #pragma unroll
    for (int off = 32; off; off >>= 1) v = fmaxf(v, __shfl_xor(v, off, 64));
    return v;
}

// Reduce 8 independent 64-lane sums simultaneously.
// Returns: every lane holds the full sum of edge e = (lane>>3)&7.
__device__ __forceinline__ float tree_reduce8(float v0, float v1, float v2, float v3,
                                              float v4, float v5, float v6, float v7,
                                              int lane) {
    const bool b5 = lane & 32, b4 = lane & 16, b3 = lane & 8;
    float w0, w1, w2, w3;
    {
        float s0 = __shfl_xor(v0, 32, 64), s1 = __shfl_xor(v1, 32, 64);
        float s2 = __shfl_xor(v2, 32, 64), s3 = __shfl_xor(v3, 32, 64);
        float s4 = __shfl_xor(v4, 32, 64), s5 = __shfl_xor(v5, 32, 64);
        float s6 = __shfl_xor(v6, 32, 64), s7 = __shfl_xor(v7, 32, 64);
        w0 = b5 ? (v4 + s4) : (v0 + s0);
        w1 = b5 ? (v5 + s5) : (v1 + s1);
        w2 = b5 ? (v6 + s6) : (v2 + s2);
        w3 = b5 ? (v7 + s7) : (v3 + s3);
    }
    float u0, u1;
    {
        float s0 = __shfl_xor(w0, 16, 64), s1 = __shfl_xor(w1, 16, 64);
        float s2 = __shfl_xor(w2, 16, 64), s3 = __shfl_xor(w3, 16, 64);
        u0 = b4 ? (w2 + s2) : (w0 + s0);
        u1 = b4 ? (w3 + s3) : (w1 + s1);
    }
    float t;
    {
        float s0 = __shfl_xor(u0, 8, 64), s1 = __shfl_xor(u1, 8, 64);
        t = b3 ? (u1 + s1) : (u0 + s0);
    }
    t += __shfl_xor(t, 4, 64);
    t += __shfl_xor(t, 2, 64);
    t += __shfl_xor(t, 1, 64);
    return t;   // edge id = b5*4 + b4*2 + b3 = (lane>>3)&7
}

// out = ent (f32), xh0 = fp16(ent)
__global__ void init_kernel(const float4* __restrict__ ent4,
                            float4* __restrict__ out4,
                            ushort4* __restrict__ xh4, int n4) {
    int i = blockIdx.x * blockDim.x + threadIdx.x;
    if (i >= n4) return;
    float4 v = ent4[i];
    out4[i] = v;
    ushort4 b;
    b.x = __half_as_ushort(__float2half(v.x));
    b.y = __half_as_ushort(__float2half(v.y));
    b.z = __half_as_ushort(__float2half(v.z));
    b.w = __half_as_ushort(__float2half(v.w));
    xh4[i] = b;
}

__global__ void hist_kernel(const int* __restrict__ head, int* __restrict__ counts, int E) {
    int e = blockIdx.x * blockDim.x + threadIdx.x;
    if (e < E) atomicAdd(&counts[head[e]], 1);
}

// ---- parallel scan: A) per-block sums, B) scan block sums, C) per-block scan ----
__global__ void bsum_kernel(const int* __restrict__ counts, int* __restrict__ bsum, int N) {
    int tid = threadIdx.x;
    int i = blockIdx.x * 1024 + tid;
    int v = (i < N) ? counts[i] : 0;
    int lane = tid & 63, wid = tid >> 6;
    #pragma unroll
    for (int off = 32; off; off >>= 1) v += __shfl_xor(v, off, 64);
    __shared__ int ws[16];
    if (lane == 0) ws[wid] = v;
    __syncthreads();
    if (tid == 0) {
        int a = 0;
        #pragma unroll
        for (int k = 0; k < 16; ++k) a += ws[k];
        bsum[blockIdx.x] = a;
    }
}

__global__ void bscan_kernel(const int* __restrict__ bsum, int* __restrict__ boff, int nb) {
    if (nb > 64) {                      // safety fallback (not hit at N=50000)
        if (threadIdx.x == 0) {
            int a = 0;
            for (int i = 0; i < nb; ++i) { boff[i] = a; a += bsum[i]; }
        }
        return;
    }
    int lane = threadIdx.x;
    int v = (lane < nb) ? bsum[lane] : 0;
    int inc = v;
    #pragma unroll
    for (int off = 1; off < 64; off <<= 1) {
        int t = __shfl_up(inc, off, 64);
        if (lane >= off) inc += t;
    }
    if (lane < nb) boff[lane] = inc - v;   // exclusive
}

__global__ void scan2_kernel(const int* __restrict__ counts,
                             const int* __restrict__ boff,
                             int* __restrict__ row_ptr,
                             int* __restrict__ cursor, int N, int E) {
    int tid = threadIdx.x;
    int i = blockIdx.x * 1024 + tid;
    int v = (i < N) ? counts[i] : 0;
    int lane = tid & 63, wid = tid >> 6;
    int inc = v;
    #pragma unroll
    for (int off = 1; off < 64; off <<= 1) {
        int t = __shfl_up(inc, off, 64);
        if (lane >= off) inc += t;
    }
    __shared__ int wsum[16], wpre[16];
    if (lane == 63) wsum[wid] = inc;
    __syncthreads();
    if (tid == 0) {
        int a = 0;
        #pragma unroll
        for (int k = 0; k < 16; ++k) { wpre[k] = a; a += wsum[k]; }
    }
    __syncthreads();
    int excl = boff[blockIdx.x] + wpre[wid] + inc - v;
    if (i < N) { row_ptr[i] = excl; cursor[i] = excl; }
    if (i == 0) row_ptr[N] = E;
}

__global__ void scatter_kernel(const int* __restrict__ head,
                               const int* __restrict__ tail,
                               const int* __restrict__ etype,
                               int* __restrict__ cursor,
                               int* __restrict__ packed, int E) {
    int e = blockIdx.x * blockDim.x + threadIdx.x;
    if (e >= E) return;
    int h = head[e];
    int pos = atomicAdd(&cursor[h], 1);
    packed[pos] = (tail[e] & TMASK) | ((etype[e] - 1) << 20);
}

// wave per node: kg scores (8-wide gathers + tree reduce) + stable softmax
__global__ void score_softmax_kernel(const float* __restrict__ ent,
                                     const __half* __restrict__ enth,
                                     const float* __restrict__ relemb,
                                     const int* __restrict__ row_ptr,
                                     const int* __restrict__ packed,
                                     float* __restrict__ score, int N, int R) {
    __shared__ float srel[2048];
    for (int i = threadIdx.x; i < R * DIM; i += blockDim.x) srel[i] = relemb[i];
    __syncthreads();
    int w    = (blockIdx.x * blockDim.x + threadIdx.x) >> 6;
    int lane = threadIdx.x & 63;
    if (w >= N) return;
    int beg = row_ptr[w], end = row_ptr[w + 1];
    if (beg == end) return;
    float eh = ent[w * DIM + lane];
    float m = -3.4e38f;
    for (int base = beg; base < end; base += 64) {
        int n = min(64, end - base);
        int p = 0;
        if (lane < n) p = packed[base + lane];
        int j = 0;
        for (; j + 8 <= n; j += 8) {
            int p0 = __shfl(p, j, 64),     p1 = __shfl(p, j + 1, 64);
            int p2 = __shfl(p, j + 2, 64), p3 = __shfl(p, j + 3, 64);
            int p4 = __shfl(p, j + 4, 64), p5 = __shfl(p, j + 5, 64);
            int p6 = __shfl(p, j + 6, 64), p7 = __shfl(p, j + 7, 64);
            float g0 = __half2float(enth[(p0 & TMASK) * DIM + lane]);
            float g1 = __half2float(enth[(p1 & TMASK) * DIM + lane]);
            float g2 = __half2float(enth[(p2 & TMASK) * DIM + lane]);
            float g3 = __half2float(enth[(p3 & TMASK) * DIM + lane]);
            float g4 = __half2float(enth[(p4 & TMASK) * DIM + lane]);
            float g5 = __half2float(enth[(p5 & TMASK) * DIM + lane]);
            float g6 = __half2float(enth[(p6 & TMASK) * DIM + lane]);
            float g7 = __half2float(enth[(p7 & TMASK) * DIM + lane]);
            float v0 = eh * srel[(p0 >> 20) * DIM + lane] * g0;
            float v1 = eh * srel[(p1 >> 20) * DIM + lane] * g1;
            float v2 = eh * srel[(p2 >> 20) * DIM + lane] * g2;
            float v3 = eh * srel[(p3 >> 20) * DIM + lane] * g3;
            float v4 = eh * srel[(p4 >> 20) * DIM + lane] * g4;
            float v5 = eh * srel[(p5 >> 20) * DIM + lane] * g5;
            float v6 = eh * srel[(p6 >> 20) * DIM + lane] * g6;
            float v7 = eh * srel[(p7 >> 20) * DIM + lane] * g7;
            float t = tree_reduce8(v0, v1, v2, v3, v4, v5, v6, v7, lane);
            if ((lane & 7) == 0) score[base + j + (lane >> 3)] = t;
            m = fmaxf(m, t);
        }
        for (; j < n; ++j) {
            int pj = __shfl(p, j, 64);
            float v = wave_sum(eh * srel[(pj >> 20) * DIM + lane] *
                               __half2float(enth[(pj & TMASK) * DIM + lane]));
            if (lane == 0) score[base + j] = v;
            m = fmaxf(m, v);
        }
    }
    m = wave_max(m);
    float s = 0.f;
    for (int i = beg + lane; i < end; i += 64) {
        float v = __expf(score[i] - m);
        score[i] = v;
        s += v;
    }
    s = wave_sum(s);
    float inv = 1.0f / s;
    for (int i = beg + lane; i < end; i += 64) score[i] *= inv;
}

// wave per node: agg = sum(score * rel * x_old[tail]); normalize; out +=; x_new (fp16)
__global__ void hop_kernel(const float* __restrict__ relemb,
                           const int* __restrict__ row_ptr,
                           const int* __restrict__ packed,
                           const float* __restrict__ score,
                           const __half* __restrict__ xh_old,
                           __half* __restrict__ xh_new,
                           float* __restrict__ out, int N, int R) {
    __shared__ float srel[2048];
    for (int i = threadIdx.x; i < R * DIM; i += blockDim.x) srel[i] = relemb[i];
    __syncthreads();
    int w    = (blockIdx.x * blockDim.x + threadIdx.x) >> 6;
    int lane = threadIdx.x & 63;
    if (w >= N) return;
    int beg = row_ptr[w], end = row_ptr[w + 1];
    float acc = 0.f;
    for (int base = beg; base < end; base += 64) {
        int n = min(64, end - base);
        int   p  = 0;
        float sc = 0.f;
        if (lane < n) { p = packed[base + lane]; sc = score[base + lane]; }
        int j = 0;
        for (; j + 8 <= n; j += 8) {
            int   p0 = __shfl(p, j, 64),     p1 = __shfl(p, j + 1, 64);
            int   p2 = __shfl(p, j + 2, 64), p3 = __shfl(p, j + 3, 64);
            int   p4 = __shfl(p, j + 4, 64), p5 = __shfl(p, j + 5, 64);
            int   p6 = __shfl(p, j + 6, 64), p7 = __shfl(p, j + 7, 64);
            float s0 = __shfl(sc, j, 64),     s1 = __shfl(sc, j + 1, 64);
            float s2 = __shfl(sc, j + 2, 64), s3 = __shfl(sc, j + 3, 64);
            float s4 = __shfl(sc, j + 4, 64), s5 = __shfl(sc, j + 5, 64);
            float s6 = __shfl(sc, j + 6, 64), s7 = __shfl(sc, j + 7, 64);
            float a0 = __half2float(xh_old[(p0 & TMASK) * DIM + lane]);
            float a1 = __half2float(xh_old[(p1 & TMASK) * DIM + lane]);
            float a2 = __half2float(xh_old[(p2 & TMASK) * DIM + lane]);
            float a3 = __half2float(xh_old[(p3 & TMASK) * DIM + lane]);
            float a4 = __half2float(xh_old[(p4 & TMASK) * DIM + lane]);
            float a5 = __half2float(xh_old[(p5 & TMASK) * DIM + lane]);
            float a6 = __half2float(xh_old[(p6 & TMASK) * DIM + lane]);
            float a7 = __half2float(xh_old[(p7 & TMASK) * DIM + lane]);
            acc += s0 * srel[(p0 >> 20) * DIM + lane] * a0;
            acc += s1 * srel[(p1 >> 20) * DIM + lane] * a1;
            acc += s2 * srel[(p2 >> 20) * DIM + lane] * a2;
            acc += s3 * srel[(p3 >> 20) * DIM + lane] * a3;
            acc += s4 * srel[(p4 >> 20) * DIM + lane] * a4;
            acc += s5 * srel[(p5 >> 20) * DIM + lane] * a5;
            acc += s6 * srel[(p6 >> 20) * DIM + lane] * a6;
            acc += s7 * srel[(p7 >> 20) * DIM + lane] * a7;
        }
        for (; j + 4 <= n; j += 4) {
            int   p0 = __shfl(p, j, 64),     p1 = __shfl(p, j + 1, 64);
            int   p2 = __shfl(p, j + 2, 64), p3 = __shfl(p, j + 3, 64);
            float s0 = __shfl(sc, j, 64),     s1 = __shfl(sc, j + 1, 64);
            float s2 = __shfl(sc, j + 2, 64), s3 = __shfl(sc, j + 3, 64);
            float a0 = __half2float(xh_old[(p0 & TMASK) * DIM + lane]);
            float a1 = __half2float(xh_old[(p1 & TMASK) * DIM + lane]);
            float a2 = __half2float(xh_old[(p2 & TMASK) * DIM + lane]);
            float a3 = __half2float(xh_old[(p3 & TMASK) * DIM + lane]);
            acc += s0 * srel[(p0 >> 20) * DIM + lane] * a0;
            acc += s1 * srel[(p1 >> 20) * DIM + lane] * a1;
            acc += s2 * srel[(p2 >> 20) * DIM + lane] * a2;
            acc += s3 * srel[(p3 >> 20) * DIM + lane] * a3;
        }
        for (; j < n; ++j) {
            int   pj = __shfl(p, j, 64);
            float sj = __shfl(sc, j, 64);
            acc += sj * srel[(pj >> 20) * DIM + lane] *
                   __half2float(xh_old[(pj & TMASK) * DIM + lane]);
        }
    }
    float s = wave_sum(acc * acc);
    float xn = acc / fmaxf(sqrtf(s), EPS);
    xh_new[w * DIM + lane] = __float2half(xn);
    out[w * DIM + lane]  += xn;
}

extern "C" void kernel_launch(void* const* d_in, const int* in_sizes, int n_in,
                              void* d_out, int out_size, void* d_ws, size_t ws_size,
                              hipStream_t stream) {
    const float* ent    = (const float*)d_in[0];
    const float* relemb = (const float*)d_in[1];
    const int*   eidx   = (const int*)d_in[2];
    const int*   etype  = (const int*)d_in[3];
    float* out = (float*)d_out;

    const int N = in_sizes[0] / DIM;   // 50000
    const int R = in_sizes[1] / DIM;   // 20
    const int E = in_sizes[3];         // 800000
    const int* head = eidx;
    const int* tail = eidx + E;

    char* ws = (char*)d_ws;
    size_t off = 0;
    auto alloc = [&](size_t bytes) {
        char* p = ws + off;
        off += (bytes + 255) & ~size_t(255);
        return p;
    };
    int*   counts  = (int*)alloc((size_t)N * 4);
    int*   row_ptr = (int*)alloc((size_t)(N + 1) * 4);
    int*   cursor  = (int*)alloc((size_t)N * 4);
    int*   bsum    = (int*)alloc(64 * 4);
    int*   boff    = (int*)alloc(64 * 4);
    int*   packed  = (int*)alloc((size_t)E * 4);
    float* score   = (float*)alloc((size_t)E * 4);
    __half* xh0    = (__half*)alloc((size_t)N * DIM * 2);
    __half* xh1    = (__half*)alloc((size_t)N * DIM * 2);
    (void)ws_size;

    hipMemsetAsync(counts, 0, (size_t)N * 4, stream);

    // init out = ent, xh0 = fp16(ent)  (xh0 doubles as the score-phase gather copy)
    {
        int n4 = N * DIM / 4;
        init_kernel<<<(n4 + 255) / 256, 256, 0, stream>>>(
            (const float4*)ent, (float4*)out, (ushort4*)xh0, n4);
    }

    // CSR by head (parallel scan)
    int nb = (N + 1023) / 1024;
    hist_kernel<<<(E + 255) / 256, 256, 0, stream>>>(head, counts, E);
    bsum_kernel<<<nb, 1024, 0, stream>>>(counts, bsum, N);
    bscan_kernel<<<1, 64, 0, stream>>>(bsum, boff, nb);
    scan2_kernel<<<nb, 1024, 0, stream>>>(counts, boff, row_ptr, cursor, N, E);
    scatter_kernel<<<(E + 255) / 256, 256, 0, stream>>>(head, tail, etype, cursor,
                                                        packed, E);

    int nodeBlocks = (N + 3) / 4;   // 4 waves / block
    score_softmax_kernel<<<nodeBlocks, 256, 0, stream>>>(ent, xh0, relemb, row_ptr,
                                                         packed, score, N, R);

    // 3 hops, ping-pong fp16 x
    hop_kernel<<<nodeBlocks, 256, 0, stream>>>(relemb, row_ptr, packed, score, xh0, xh1, out, N, R);
    hop_kernel<<<nodeBlocks, 256, 0, stream>>>(relemb, row_ptr, packed, score, xh1, xh0, out, N, R);
    hop_kernel<<<nodeBlocks, 256, 0, stream>>>(relemb, row_ptr, packed, score, xh0, xh1, out, N, R);
}